// Round 1
// baseline (122.855 us; speedup 1.0000x reference)
//
#include <hip/hip_runtime.h>
#include <math.h>

#define NB 32
#define NQ 256
#define NK 256
#define NH 128
#define QT 16          // q rows per block (one per wave)
#define KT 64          // k tile (one row per lane)
#define LOG2E 1.4426950408889634f

__global__ __launch_bounds__(1024) void addattn_kernel(
    const float* __restrict__ q_g, const float* __restrict__ k_g,
    const float* __restrict__ v_g, const float* __restrict__ w_g,
    float* __restrict__ out)
{
    // buf: union of keys tile (quad-transposed [32][256]) and V tile (linear [64][128]) = 32KB
    __shared__ float buf[8192];
    __shared__ float attn_lds[QT * NK];   // 16KB

    const int tid  = threadIdx.x;
    const int lane = tid & 63;
    const int wv   = __builtin_amdgcn_readfirstlane(tid >> 6);  // wave id, forced uniform
    const int b    = blockIdx.x >> 4;
    const int q0   = (blockIdx.x & 15) * QT;

    // wave-uniform pointers -> scalar-load path for q row and w
    const float* qrow = q_g + (size_t)(b * NQ + q0 + wv) * NH;

    float score[4];
    #pragma unroll 1
    for (int kt = 0; kt < 4; ++kt) {
        __syncthreads();
        // stage keys tile: coalesced float4 loads, quad-transposed rotation-swizzled LDS writes
        {
            const float4* src = (const float4*)(k_g + (size_t)(b * NK + kt * KT) * NH);
            #pragma unroll
            for (int j = 0; j < 2; ++j) {
                int e4 = tid + j * 1024;          // 2048 float4 per tile
                float4 d = src[e4];
                int kr = e4 >> 5;                 // k row within tile (0..63)
                int h4 = e4 & 31;                 // h-chunk (0..31)
                *((float4*)&buf[h4 * 256 + (((kr + h4) & 63) << 2)]) = d;
            }
        }
        __syncthreads();

        float acc = 0.f;
        #pragma unroll 4
        for (int h4 = 0; h4 < 32; ++h4) {
            float4 q4 = *(const float4*)&qrow[h4 << 2];          // wave-uniform
            float4 w4 = *(const float4*)&w_g[h4 << 2];           // uniform
            float4 k4 = *(const float4*)&buf[h4 * 256 + (((lane + h4) & 63) << 2)];
            #pragma unroll
            for (int i = 0; i < 4; ++i) {
                float x = ((&q4.x)[i] + (&k4.x)[i]) * (2.0f * LOG2E);
                float e = exp2f(x);                               // v_exp_f32
                float t = 1.0f - 2.0f * __builtin_amdgcn_rcpf(e + 1.0f);  // tanh
                acc = fmaf(t, (&w4.x)[i], acc);
            }
        }
        score[kt] = acc;   // k = kt*64 + lane
    }

    // softmax over 256 scores distributed 4-per-lane across 64 lanes
    float m = fmaxf(fmaxf(score[0], score[1]), fmaxf(score[2], score[3]));
    #pragma unroll
    for (int off = 32; off; off >>= 1) m = fmaxf(m, __shfl_xor(m, off));
    float ev[4], ssum = 0.f;
    #pragma unroll
    for (int j = 0; j < 4; ++j) { ev[j] = exp2f((score[j] - m) * LOG2E); ssum += ev[j]; }
    #pragma unroll
    for (int off = 32; off; off >>= 1) ssum += __shfl_xor(ssum, off);
    float inv = __builtin_amdgcn_rcpf(ssum);
    #pragma unroll
    for (int j = 0; j < 4; ++j) attn_lds[wv * NK + j * 64 + lane] = ev[j] * inv;

    // PV: out[h] = sum_k attn[k] * V[k][h]; lane owns h = 2*lane, 2*lane+1
    float a0 = 0.f, a1 = 0.f;
    #pragma unroll 1
    for (int vt = 0; vt < 4; ++vt) {
        __syncthreads();
        {
            const float4* src = (const float4*)(v_g + (size_t)(b * NK + vt * KT) * NH);
            ((float4*)buf)[tid]        = src[tid];
            ((float4*)buf)[tid + 1024] = src[tid + 1024];
        }
        __syncthreads();
        #pragma unroll 4
        for (int kk = 0; kk < 16; ++kk) {
            float4 at = *(const float4*)&attn_lds[wv * NK + vt * KT + (kk << 2)];  // uniform bcast
            #pragma unroll
            for (int i = 0; i < 4; ++i) {
                float2 v2 = *(const float2*)&buf[(kk * 4 + i) * NH + (lane << 1)];
                a0 = fmaf((&at.x)[i], v2.x, a0);
                a1 = fmaf((&at.x)[i], v2.y, a1);
            }
        }
    }

    float2 o; o.x = a0; o.y = a1;
    *(float2*)&out[(size_t)(b * NQ + q0 + wv) * NH + (lane << 1)] = o;
}

extern "C" void kernel_launch(void* const* d_in, const int* in_sizes, int n_in,
                              void* d_out, int out_size, void* d_ws, size_t ws_size,
                              hipStream_t stream) {
    const float* q = (const float*)d_in[0];
    const float* k = (const float*)d_in[1];
    const float* v = (const float*)d_in[2];
    const float* w = (const float*)d_in[3];
    float* out = (float*)d_out;
    addattn_kernel<<<NB * (NQ / QT), 1024, 0, stream>>>(q, k, v, w, out);
}

// Round 2
// 87.634 us; speedup vs baseline: 1.4019x; 1.4019x over previous
//
#include <hip/hip_runtime.h>
#include <math.h>

#define NB 32
#define NQ 256
#define NK 256
#define NH 128
#define QT 16          // q rows per block (one per wave)
#define C2 2.8853900817779268f   // 2*log2(e)
#define LOG2E 1.4426950408889634f

__global__ __launch_bounds__(1024) void addattn_kernel(
    const float* __restrict__ q_g, const float* __restrict__ k_g,
    const float* __restrict__ v_g, const float* __restrict__ w_g,
    float* __restrict__ out)
{
    // kbuf: two 64-row k-tiles (quad-transposed, rotation-swizzled, pre-scaled) = 64KB
    //       reused for V tiles (linear [128][128]) in PV phase
    __shared__ float kbuf[16384];
    // wbuf: per-wave 256-float private strip: qs (scaled q row) during score phase,
    //       attn weights during PV phase. 16KB.
    __shared__ float wbuf[QT * 256];

    const int tid  = threadIdx.x;
    const int lane = tid & 63;
    const int wv   = tid >> 6;
    const int b    = blockIdx.x >> 4;
    const int q0   = (blockIdx.x & 15) * QT;

    // per-wave: load q row, pre-scale by 2*log2e, stash in wbuf[wv*256 + 0..127]
    {
        const float* qrow = q_g + (size_t)(b * NQ + q0 + wv) * NH;
        float2 qv = *(const float2*)&qrow[lane * 2];
        float2 qs; qs.x = qv.x * C2; qs.y = qv.y * C2;
        *(float2*)&wbuf[wv * 256 + lane * 2] = qs;
    }

    float acc[4];

    #pragma unroll 1
    for (int half = 0; half < 2; ++half) {
        __syncthreads();
        // stage k rows [half*128, half*128+128): pre-scaled, swizzled, both tiles
        {
            const float4* src = (const float4*)(k_g + (size_t)(b * NK + half * 128) * NH);
            #pragma unroll
            for (int j = 0; j < 4; ++j) {
                int e4 = tid + j * 1024;        // 0..4095 float4
                float4 d = src[e4];
                d.x *= C2; d.y *= C2; d.z *= C2; d.w *= C2;
                int kr = e4 >> 5;               // 0..127
                int h4 = e4 & 31;
                int t  = kr >> 6;               // tile within half
                int k6 = kr & 63;
                *((float4*)&kbuf[t * 8192 + h4 * 256 + (((k6 + h4) & 63) << 2)]) = d;
            }
        }
        __syncthreads();

        float a0 = 0.f, a1 = 0.f;
        #pragma unroll 8
        for (int h4 = 0; h4 < 32; ++h4) {
            float4 w4 = *(const float4*)&w_g[h4 << 2];                         // uniform
            float4 q4 = *(const float4*)&wbuf[wv * 256 + (h4 << 2)];          // uniform bcast
            float4 kA = *(const float4*)&kbuf[h4 * 256 + (((lane + h4) & 63) << 2)];
            float4 kB = *(const float4*)&kbuf[8192 + h4 * 256 + (((lane + h4) & 63) << 2)];
            #pragma unroll
            for (int i = 0; i < 4; ++i) {
                float xA = (&q4.x)[i] + (&kA.x)[i];
                float xB = (&q4.x)[i] + (&kB.x)[i];
                float eA = __builtin_amdgcn_exp2f(xA);
                float eB = __builtin_amdgcn_exp2f(xB);
                float rA = __builtin_amdgcn_rcpf(eA + 1.0f);
                float rB = __builtin_amdgcn_rcpf(eB + 1.0f);
                a0 = fmaf((&w4.x)[i], rA, a0);
                a1 = fmaf((&w4.x)[i], rB, a1);
            }
        }
        acc[half * 2]     = a0;   // k = (half*2)*64 + lane
        acc[half * 2 + 1] = a1;   // k = (half*2+1)*64 + lane
    }

    // scores s[j] = -2*acc[j] (Σw term is k-uniform -> cancels in softmax)
    float s[4];
    #pragma unroll
    for (int j = 0; j < 4; ++j) s[j] = -2.0f * acc[j];
    float m = fmaxf(fmaxf(s[0], s[1]), fmaxf(s[2], s[3]));
    #pragma unroll
    for (int off = 32; off; off >>= 1) m = fmaxf(m, __shfl_xor(m, off));
    float ev[4], ssum = 0.f;
    #pragma unroll
    for (int j = 0; j < 4; ++j) {
        ev[j] = __builtin_amdgcn_exp2f((s[j] - m) * LOG2E);
        ssum += ev[j];
    }
    #pragma unroll
    for (int off = 32; off; off >>= 1) ssum += __shfl_xor(ssum, off);
    float inv = __builtin_amdgcn_rcpf(ssum);
    // attn into the wave-private strip (qs no longer needed; no barrier required)
    #pragma unroll
    for (int j = 0; j < 4; ++j) wbuf[wv * 256 + j * 64 + lane] = ev[j] * inv;

    // PV: out[h] = sum_k attn[k] * V[k][h]; lane owns h = lane and h = 64+lane
    float o0 = 0.f, o1 = 0.f;
    #pragma unroll 1
    for (int half = 0; half < 2; ++half) {
        __syncthreads();
        {   // stage V rows [half*128, half*128+128) linear [128][128]
            const float4* src = (const float4*)(v_g + (size_t)(b * NK + half * 128) * NH);
            #pragma unroll
            for (int j = 0; j < 4; ++j)
                ((float4*)kbuf)[tid + j * 1024] = src[tid + j * 1024];
        }
        __syncthreads();
        #pragma unroll 4
        for (int g = 0; g < 32; ++g) {
            float4 at = *(const float4*)&wbuf[wv * 256 + half * 128 + (g << 2)]; // uniform
            #pragma unroll
            for (int i = 0; i < 4; ++i) {
                int row = (g << 2) + i;
                float vx = kbuf[row * NH + lane];
                float vy = kbuf[row * NH + 64 + lane];
                o0 = fmaf((&at.x)[i], vx, o0);
                o1 = fmaf((&at.x)[i], vy, o1);
            }
        }
    }

    float* orow = out + (size_t)(b * NQ + q0 + wv) * NH;
    orow[lane]      = o0;
    orow[64 + lane] = o1;
}

extern "C" void kernel_launch(void* const* d_in, const int* in_sizes, int n_in,
                              void* d_out, int out_size, void* d_ws, size_t ws_size,
                              hipStream_t stream) {
    const float* q = (const float*)d_in[0];
    const float* k = (const float*)d_in[1];
    const float* v = (const float*)d_in[2];
    const float* w = (const float*)d_in[3];
    float* out = (float*)d_out;
    addattn_kernel<<<NB * (NQ / QT), 1024, 0, stream>>>(q, k, v, w, out);
}

// Round 3
// 58.947 us; speedup vs baseline: 2.0841x; 1.4866x over previous
//
#include <hip/hip_runtime.h>
#include <math.h>

#define NB 32
#define NQ 256
#define NK 256
#define NH 128
#define C2 2.8853900817779268f   // 2*log2(e)
#define LOG2E 1.4426950408889634f

__global__ __launch_bounds__(1024, 4) void addattn_kernel(
    const float* __restrict__ q_g, const float* __restrict__ k_g,
    const float* __restrict__ v_g, const float* __restrict__ w_g,
    float* __restrict__ out)
{
    __shared__ float kbuf[16384];      // 64 KB: 2 x 32KB double-buffered 64-row tiles (Ek, then V)
    __shared__ float strip[4096];      // 16 KB: per-wave 256 f32 (Eq during score; attn slices during PV)

    const int tid  = threadIdx.x;
    const int lane = tid & 63;
    const int wv   = tid >> 6;
    const int kk   = lane & 31;        // k (score) / h (PV) sub-index
    const int qh   = lane >> 5;        // which of the wave's 2 q rows

    // XCD-grouped remap: 8 blocks of one batch land on one XCD's L2
    const int o  = ((blockIdx.x & 7) << 5) + (blockIdx.x >> 3);
    const int b  = o >> 3;
    const int q0 = (o & 7) << 5;       // 32 q rows per block (16 waves x 2)

    // ---- Eq = exp2(C2*q) into wave-private strip ----
    {
        const float* qp = q_g + ((size_t)(b * NQ + q0 + (wv << 1) + qh)) * NH + (kk << 2);
        float4 qv = *(const float4*)qp;
        float4 E;
        E.x = __builtin_amdgcn_exp2f(C2 * qv.x);
        E.y = __builtin_amdgcn_exp2f(C2 * qv.y);
        E.z = __builtin_amdgcn_exp2f(C2 * qv.z);
        E.w = __builtin_amdgcn_exp2f(C2 * qv.w);
        *(float4*)&strip[(wv << 8) + (qh << 7) + (kk << 2)] = E;
    }

    const float4* kg4 = (const float4*)(k_g + (size_t)b * NK * NH);
    const float4* vg4 = (const float4*)(v_g + (size_t)b * NK * NH);

    // ---- K tile 0 prologue: load -> exp2 -> swizzled LDS ----
    {
        float4 pa = kg4[tid];
        float4 pb = kg4[tid + 1024];
        int kr = tid >> 5, h4 = tid & 31;
        float4 EA, EB;
        EA.x = __builtin_amdgcn_exp2f(C2 * pa.x); EA.y = __builtin_amdgcn_exp2f(C2 * pa.y);
        EA.z = __builtin_amdgcn_exp2f(C2 * pa.z); EA.w = __builtin_amdgcn_exp2f(C2 * pa.w);
        EB.x = __builtin_amdgcn_exp2f(C2 * pb.x); EB.y = __builtin_amdgcn_exp2f(C2 * pb.y);
        EB.z = __builtin_amdgcn_exp2f(C2 * pb.z); EB.w = __builtin_amdgcn_exp2f(C2 * pb.w);
        *(float4*)&kbuf[(h4 << 8) + (((kr + h4) & 63) << 2)]      = EA;
        *(float4*)&kbuf[(h4 << 8) + (((kr + 32 + h4) & 63) << 2)] = EB;
    }
    __syncthreads();

    // ---- score phase: 4 tiles of 64 k-rows, double-buffered ----
    float sc[8];
    const float* wvEq = strip + (wv << 8) + (qh << 7);
    #pragma unroll
    for (int t = 0; t < 4; ++t) {
        float4 pa, pb;
        if (t < 3) {                                    // T14: issue next-tile loads early
            pa = kg4[(t + 1) * 2048 + tid];
            pb = kg4[(t + 1) * 2048 + tid + 1024];
        }
        const float* kb = kbuf + ((t & 1) << 13);
        float sA = 0.f, sB = 0.f;
        #pragma unroll 4
        for (int h4 = 0; h4 < 32; ++h4) {
            float4 w4 = *(const float4*)(w_g + (h4 << 2));               // scalar path
            float4 e4 = *(const float4*)(wvEq + (h4 << 2));              // 2-addr broadcast
            float4 kA = *(const float4*)(kb + (h4 << 8) + (((kk + h4) & 63) << 2));
            float4 kB = *(const float4*)(kb + (h4 << 8) + (((kk + 32 + h4) & 63) << 2));
            #pragma unroll
            for (int i = 0; i < 4; ++i) {
                float eq = (&e4.x)[i], wi = (&w4.x)[i];
                float tA = fmaf(eq, (&kA.x)[i], 1.0f);
                float tB = fmaf(eq, (&kB.x)[i], 1.0f);
                sA = fmaf(wi, __builtin_amdgcn_rcpf(tA), sA);
                sB = fmaf(wi, __builtin_amdgcn_rcpf(tB), sB);
            }
        }
        sc[2 * t]     = sA;     // k = t*64 + kk
        sc[2 * t + 1] = sB;     // k = t*64 + 32 + kk
        if (t < 3) {                                    // transform + write next tile
            int kr = tid >> 5, h4 = tid & 31;
            float4 EA, EB;
            EA.x = __builtin_amdgcn_exp2f(C2 * pa.x); EA.y = __builtin_amdgcn_exp2f(C2 * pa.y);
            EA.z = __builtin_amdgcn_exp2f(C2 * pa.z); EA.w = __builtin_amdgcn_exp2f(C2 * pa.w);
            EB.x = __builtin_amdgcn_exp2f(C2 * pb.x); EB.y = __builtin_amdgcn_exp2f(C2 * pb.y);
            EB.z = __builtin_amdgcn_exp2f(C2 * pb.z); EB.w = __builtin_amdgcn_exp2f(C2 * pb.w);
            float* kbn = kbuf + (((t + 1) & 1) << 13);
            *(float4*)&kbn[(h4 << 8) + (((kr + h4) & 63) << 2)]      = EA;
            *(float4*)&kbn[(h4 << 8) + (((kr + 32 + h4) & 63) << 2)] = EB;
        }
        __syncthreads();
    }

    // ---- V tile 0 loads issued, then softmax overlaps the latency ----
    float4 va0 = vg4[tid];
    float4 vb0 = vg4[tid + 1024];

    float s[8];
    #pragma unroll
    for (int j = 0; j < 8; ++j) s[j] = -2.0f * sc[j];
    float m = s[0];
    #pragma unroll
    for (int j = 1; j < 8; ++j) m = fmaxf(m, s[j]);
    #pragma unroll
    for (int off = 16; off; off >>= 1) m = fmaxf(m, __shfl_xor(m, off));
    float ev[8], ssum = 0.f;
    #pragma unroll
    for (int j = 0; j < 8; ++j) { ev[j] = __builtin_amdgcn_exp2f((s[j] - m) * LOG2E); ssum += ev[j]; }
    #pragma unroll
    for (int off = 16; off; off >>= 1) ssum += __shfl_xor(ssum, off);
    const float inv = __builtin_amdgcn_rcpf(ssum);

    // attn slice for PV tile 0 (wave-private strip, Eq now dead)
    strip[(wv << 8) + (qh << 6) + kk]      = ev[0] * inv;
    strip[(wv << 8) + (qh << 6) + 32 + kk] = ev[1] * inv;
    ((float4*)kbuf)[tid]        = va0;      // V tile 0 -> half 0, linear
    ((float4*)kbuf)[tid + 1024] = vb0;
    __syncthreads();

    // ---- PV phase: 4 tiles of 64 V-rows, double-buffered ----
    float o0 = 0.f, o1 = 0.f, o2 = 0.f, o3 = 0.f;
    const float* atp = strip + (wv << 8) + (qh << 6);
    #pragma unroll
    for (int t = 0; t < 4; ++t) {
        float4 va, vb;
        if (t < 3) {
            va = vg4[(t + 1) * 2048 + tid];
            vb = vg4[(t + 1) * 2048 + tid + 1024];
        }
        const float* vbuf = kbuf + ((t & 1) << 13);
        #pragma unroll 4
        for (int g = 0; g < 16; ++g) {
            float4 at = *(const float4*)(atp + (g << 2));     // 2-addr broadcast
            #pragma unroll
            for (int i = 0; i < 4; ++i) {
                int r = (g << 2) + i;
                float a = (&at.x)[i];
                o0 = fmaf(a, vbuf[(r << 7) + kk],      o0);   // broadcast across half-waves
                o1 = fmaf(a, vbuf[(r << 7) + 32 + kk], o1);
                o2 = fmaf(a, vbuf[(r << 7) + 64 + kk], o2);
                o3 = fmaf(a, vbuf[(r << 7) + 96 + kk], o3);
            }
        }
        if (t < 3) {
            strip[(wv << 8) + (qh << 6) + kk]      = ev[2 * t + 2] * inv;
            strip[(wv << 8) + (qh << 6) + 32 + kk] = ev[2 * t + 3] * inv;
            float* vl = kbuf + (((t + 1) & 1) << 13);
            ((float4*)vl)[tid]        = va;
            ((float4*)vl)[tid + 1024] = vb;
        }
        __syncthreads();
    }

    float* orow = out + ((size_t)(b * NQ) + q0 + (wv << 1) + qh) * NH;
    orow[kk]      = o0;
    orow[32 + kk] = o1;
    orow[64 + kk] = o2;
    orow[96 + kk] = o3;
}

extern "C" void kernel_launch(void* const* d_in, const int* in_sizes, int n_in,
                              void* d_out, int out_size, void* d_ws, size_t ws_size,
                              hipStream_t stream) {
    const float* q = (const float*)d_in[0];
    const float* k = (const float*)d_in[1];
    const float* v = (const float*)d_in[2];
    const float* w = (const float*)d_in[3];
    float* out = (float*)d_out;
    addattn_kernel<<<NB * 8, 1024, 0, stream>>>(q, k, v, w, out);
}